// Round 1
// baseline (925.088 us; speedup 1.0000x reference)
//
#include <hip/hip_runtime.h>

constexpr int N_ROWS = 131072;
constexpr int K_CB   = 4096;
constexpr int D_DIM  = 64;
constexpr int BN     = 128;   // rows per block
constexpr int BK     = 128;   // codes per k-tile
constexpr int LDT    = 132;   // LDS tile row stride (floats), 16B-aligned rows

// ---- kernel 1: codebook squared norms -> ws ----
__global__ __launch_bounds__(256)
void csq_kernel(const float* __restrict__ cb, float* __restrict__ csq) {
    const int k = blockIdx.x * 256 + threadIdx.x;
    if (k < K_CB) {
        const float4* row = (const float4*)(cb + (long)k * D_DIM);
        float s = 0.f;
        #pragma unroll
        for (int i = 0; i < 16; ++i) {
            const float4 v = row[i];
            s += v.x * v.x + v.y * v.y + v.z * v.z + v.w * v.w;
        }
        csq[k] = s;
    }
}

// ---- kernel 2: fused distance GEMM + argmin + gather ----
__global__ __launch_bounds__(256, 2)
void vq_main_kernel(const float* __restrict__ z,
                    const float* __restrict__ cb,
                    const float* __restrict__ csq_g,
                    float* __restrict__ out) {
    __shared__ float As[D_DIM][LDT];   // A tile transposed: As[d][r]
    __shared__ float Bs[D_DIM][LDT];   // B tile transposed: Bs[d][c]
    __shared__ float csq_s[BK];
    __shared__ int   bidx[BN];

    const int t  = threadIdx.x;
    const int tx = t & 15;
    const int ty = t >> 4;
    const long n0 = (long)blockIdx.x * BN;

    // Stage A tile once (rows n0..n0+127, transposed)
    #pragma unroll
    for (int i = 0; i < 8; ++i) {
        const int ii = t + i * 256;
        const int r  = ii >> 4;
        const int c4 = ii & 15;
        const float4 v = ((const float4*)(z + (n0 + r) * D_DIM))[c4];
        As[c4 * 4 + 0][r] = v.x;
        As[c4 * 4 + 1][r] = v.y;
        As[c4 * 4 + 2][r] = v.z;
        As[c4 * 4 + 3][r] = v.w;
    }

    float bestv[8];
    int   besti[8];
    #pragma unroll
    for (int i = 0; i < 8; ++i) { bestv[i] = __builtin_inff(); besti[i] = 0; }

    for (int kt = 0; kt < K_CB; kt += BK) {
        __syncthreads();   // previous iteration done reading Bs / csq_s
        #pragma unroll
        for (int i = 0; i < 8; ++i) {
            const int ii = t + i * 256;
            const int r  = ii >> 4;
            const int c4 = ii & 15;
            const float4 v = ((const float4*)(cb + (long)(kt + r) * D_DIM))[c4];
            Bs[c4 * 4 + 0][r] = v.x;
            Bs[c4 * 4 + 1][r] = v.y;
            Bs[c4 * 4 + 2][r] = v.z;
            Bs[c4 * 4 + 3][r] = v.w;
        }
        if (t < BK) csq_s[t] = csq_g[kt + t];
        __syncthreads();

        float acc[8][8];
        #pragma unroll
        for (int i = 0; i < 8; ++i)
            #pragma unroll
            for (int j = 0; j < 8; ++j) acc[i][j] = 0.f;

        #pragma unroll 2
        for (int d = 0; d < D_DIM; ++d) {
            const float4 a0 = *(const float4*)&As[d][ty * 4];
            const float4 a1 = *(const float4*)&As[d][64 + ty * 4];
            const float4 b0 = *(const float4*)&Bs[d][tx * 4];
            const float4 b1 = *(const float4*)&Bs[d][64 + tx * 4];
            const float av[8] = {a0.x, a0.y, a0.z, a0.w, a1.x, a1.y, a1.z, a1.w};
            const float bv[8] = {b0.x, b0.y, b0.z, b0.w, b1.x, b1.y, b1.z, b1.w};
            #pragma unroll
            for (int i = 0; i < 8; ++i)
                #pragma unroll
                for (int j = 0; j < 8; ++j)
                    acc[i][j] = fmaf(av[i], bv[j], acc[i][j]);
        }

        // epilogue: s = |c|^2 - 2*dot ; running argmin with first-index tie-break
        #pragma unroll
        for (int j = 0; j < 8; ++j) {
            const int c   = (j & 3) + ((j < 4) ? (tx * 4) : (64 + tx * 4));
            const int idx = kt + c;
            const float cs = csq_s[c];
            #pragma unroll
            for (int i = 0; i < 8; ++i) {
                const float s = fmaf(acc[i][j], -2.f, cs);
                if (s < bestv[i] || (s == bestv[i] && idx < besti[i])) {
                    bestv[i] = s;
                    besti[i] = idx;
                }
            }
        }
    }

    // cross-thread (tx) argmin reduction per row, reusing LDS tiles
    __syncthreads();
    float* rval = &As[0][0];          // [BN][16] values
    int*   ridx = (int*)&Bs[0][0];    // [BN][16] indices
    #pragma unroll
    for (int i = 0; i < 8; ++i) {
        const int r = (i & 3) + ((i < 4) ? (ty * 4) : (64 + ty * 4));
        rval[r * 16 + tx] = bestv[i];
        ridx[r * 16 + tx] = besti[i];
    }
    __syncthreads();
    if (t < BN) {
        float bv = rval[t * 16];
        int   bi = ridx[t * 16];
        #pragma unroll
        for (int x = 1; x < 16; ++x) {
            const float v = rval[t * 16 + x];
            const int  ix = ridx[t * 16 + x];
            if (v < bv || (v == bv && ix < bi)) { bv = v; bi = ix; }
        }
        bidx[t] = bi;
    }
    __syncthreads();

    // gather winning codebook rows; write both output copies
    #pragma unroll
    for (int i = 0; i < 8; ++i) {
        const int ii = t + i * 256;
        const int r  = ii >> 4;
        const int c4 = ii & 15;
        const int k  = bidx[r];
        const float4 v = ((const float4*)(cb + (long)k * D_DIM))[c4];
        *((float4*)(out + (n0 + r) * D_DIM) + c4) = v;
        *((float4*)(out + (long)N_ROWS * D_DIM + (n0 + r) * D_DIM) + c4) = v;
    }
}

extern "C" void kernel_launch(void* const* d_in, const int* in_sizes, int n_in,
                              void* d_out, int out_size, void* d_ws, size_t ws_size,
                              hipStream_t stream) {
    const float* z  = (const float*)d_in[0];
    const float* cb = (const float*)d_in[1];
    float* out = (float*)d_out;
    float* csq = (float*)d_ws;   // K_CB floats = 16 KB

    csq_kernel<<<K_CB / 256, 256, 0, stream>>>(cb, csq);
    vq_main_kernel<<<N_ROWS / BN, 256, 0, stream>>>(z, cb, csq, out);
}

// Round 2
// 492.757 us; speedup vs baseline: 1.8774x; 1.8774x over previous
//
#include <hip/hip_runtime.h>

typedef __attribute__((ext_vector_type(8))) short short8;   // 8 x bf16 fragment
typedef __attribute__((ext_vector_type(4))) float f32x4;

constexpr int N_ROWS = 131072;
constexpr int K_CB   = 4096;
constexpr int D_DIM  = 64;
constexpr float EPS_MARGIN = 0.0625f;

// ---- ws layout (bytes) ----
constexpr size_t CTR_OFF   = 0;        // int counter
constexpr size_t CSQ_OFF   = 64;       // 4096 f32
constexpr size_t CBH_OFF   = 16512;    // 4096*64 bf16, pre-swizzled   (512 KB)
constexpr size_t CBL_OFF   = CBH_OFF + 524288;
constexpr size_t BESTI_OFF = CBL_OFF + 524288;   // N int
constexpr size_t LIST_OFF  = BESTI_OFF + 524288; // N int

#define MFMA(a, b, c) __builtin_amdgcn_mfma_f32_16x16x32_bf16((a), (b), (c), 0, 0, 0)

__device__ __forceinline__ unsigned short f2bf(float f) {
    unsigned int u = __builtin_bit_cast(unsigned int, f);
    u = (u + 0x7fffu + ((u >> 16) & 1u)) >> 16;   // RTNE
    return (unsigned short)u;
}
__device__ __forceinline__ float bf2f(unsigned short h) {
    return __builtin_bit_cast(float, ((unsigned int)h) << 16);
}

// swizzled 16B fragment read: row*128B row-major tile, slot XOR (row&7)
__device__ __forceinline__ short8 ldfrag(const unsigned char* smbase, int row, int lane, int ks) {
    const int slot = (((lane >> 4) + ks * 4) ^ (lane & 7));
    uint4 v = *(const uint4*)(smbase + row * 128 + slot * 16);
    return __builtin_bit_cast(short8, v);
}

// ---- prep: codebook squared norms (exact fp32) ----
__global__ __launch_bounds__(256)
void prep_csq(const float* __restrict__ cb, float* __restrict__ csq) {
    const int k = blockIdx.x * 256 + threadIdx.x;
    const float4* row = (const float4*)(cb + (size_t)k * D_DIM);
    float s = 0.f;
    #pragma unroll
    for (int i = 0; i < 16; ++i) {
        float4 v = row[i];
        s = fmaf(v.x, v.x, s); s = fmaf(v.y, v.y, s);
        s = fmaf(v.z, v.z, s); s = fmaf(v.w, v.w, s);
    }
    csq[k] = s;
}

// ---- prep: split cb into hi/lo bf16 planes, PRE-SWIZZLED (slot ^= row&7) ----
__global__ __launch_bounds__(256)
void prep_split(const float* __restrict__ cb, unsigned char* __restrict__ cbh,
                unsigned char* __restrict__ cbl) {
    const int id  = blockIdx.x * 256 + threadIdx.x;   // 32768 = 4096 rows * 8 slots
    const int row = id >> 3, s = id & 7;
    const float4* src = (const float4*)(cb + (size_t)row * D_DIM + s * 8);
    float4 v0 = src[0], v1 = src[1];
    float f[8] = {v0.x, v0.y, v0.z, v0.w, v1.x, v1.y, v1.z, v1.w};
    unsigned int hw[4], lw[4];
    #pragma unroll
    for (int i = 0; i < 4; ++i) {
        unsigned short h0 = f2bf(f[2*i]),     l0 = f2bf(f[2*i]     - bf2f(h0));
        unsigned short h1 = f2bf(f[2*i + 1]), l1 = f2bf(f[2*i + 1] - bf2f(h1));
        hw[i] = (unsigned int)h0 | ((unsigned int)h1 << 16);
        lw[i] = (unsigned int)l0 | ((unsigned int)l1 << 16);
    }
    const int slot = s ^ (row & 7);
    *(uint4*)(cbh + (size_t)row * 128 + slot * 16) = make_uint4(hw[0], hw[1], hw[2], hw[3]);
    *(uint4*)(cbl + (size_t)row * 128 + slot * 16) = make_uint4(lw[0], lw[1], lw[2], lw[3]);
}

__global__ void init_counter(int* counter) { if (threadIdx.x == 0) *counter = 0; }

// ---- stage one 128-code tile (hi 16KB + lo 16KB + csq 512B) via global_load_lds ----
__device__ __forceinline__ void stage_tile(const unsigned char* __restrict__ cbh,
                                           const unsigned char* __restrict__ cbl,
                                           const float* __restrict__ csqg,
                                           unsigned char* sm, int kt, int wid, int lane) {
    const unsigned char* sh = cbh + (size_t)kt * 128;
    const unsigned char* sl = cbl + (size_t)kt * 128;
    #pragma unroll
    for (int p = 0; p < 4; ++p) {
        const int chunk = wid * 4 + p;
        __builtin_amdgcn_global_load_lds(
            (const __attribute__((address_space(1))) void*)(sh + chunk * 1024 + lane * 16),
            (__attribute__((address_space(3))) void*)(sm + chunk * 1024), 16, 0, 0);
    }
    #pragma unroll
    for (int p = 0; p < 4; ++p) {
        const int chunk = wid * 4 + p;
        __builtin_amdgcn_global_load_lds(
            (const __attribute__((address_space(1))) void*)(sl + chunk * 1024 + lane * 16),
            (__attribute__((address_space(3))) void*)(sm + 16384 + chunk * 1024), 16, 0, 0);
    }
    if (wid < 2) {
        __builtin_amdgcn_global_load_lds(
            (const __attribute__((address_space(1))) void*)(csqg + kt + wid * 64 + lane),
            (__attribute__((address_space(3))) void*)(sm + 32768 + wid * 256), 4, 0, 0);
    }
}

// ---- main: split-bf16 MFMA distances + running argmin/second-best ----
__global__ __launch_bounds__(256, 2)
void vq_main_mfma(const float* __restrict__ z,
                  const unsigned char* __restrict__ cbh,
                  const unsigned char* __restrict__ cbl,
                  const float* __restrict__ csqg,
                  int* __restrict__ besti, int* __restrict__ list,
                  int* __restrict__ counter) {
    __shared__ __align__(16) unsigned char sm[2][33792];   // hi 16K | lo 16K | csq 512B
    const int t = threadIdx.x, lane = t & 63, wid = t >> 6;
    const int n0 = blockIdx.x * 128;
    const int wbase = wid * 32;

    // stage A tile (128 rows of z) hi/lo swizzled into sm[0]
    #pragma unroll
    for (int p = 0; p < 4; ++p) {
        const int id = t + p * 256;          // 1024 = 128 rows * 8 slots
        const int row = id >> 3, s = id & 7;
        const float4* src = (const float4*)(z + (size_t)(n0 + row) * D_DIM + s * 8);
        float4 v0 = src[0], v1 = src[1];
        float f[8] = {v0.x, v0.y, v0.z, v0.w, v1.x, v1.y, v1.z, v1.w};
        unsigned int hw[4], lw[4];
        #pragma unroll
        for (int i = 0; i < 4; ++i) {
            unsigned short h0 = f2bf(f[2*i]),     l0 = f2bf(f[2*i]     - bf2f(h0));
            unsigned short h1 = f2bf(f[2*i + 1]), l1 = f2bf(f[2*i + 1] - bf2f(h1));
            hw[i] = (unsigned int)h0 | ((unsigned int)h1 << 16);
            lw[i] = (unsigned int)l0 | ((unsigned int)l1 << 16);
        }
        const int slot = s ^ (row & 7);
        *(uint4*)(&sm[0][row * 128 + slot * 16])         = make_uint4(hw[0], hw[1], hw[2], hw[3]);
        *(uint4*)(&sm[0][16384 + row * 128 + slot * 16]) = make_uint4(lw[0], lw[1], lw[2], lw[3]);
    }
    __syncthreads();

    short8 ah[2][2], al[2][2];
    #pragma unroll
    for (int m = 0; m < 2; ++m)
        #pragma unroll
        for (int ks = 0; ks < 2; ++ks) {
            const int row = wbase + m * 16 + (lane & 15);
            ah[m][ks] = ldfrag(&sm[0][0],     row, lane, ks);
            al[m][ks] = ldfrag(&sm[0][16384], row, lane, ks);
        }
    __syncthreads();   // everyone done reading A before B staging overwrites

    float b1[2][4], b2[2][4]; int i1[2][4];
    #pragma unroll
    for (int m = 0; m < 2; ++m)
        #pragma unroll
        for (int r = 0; r < 4; ++r) { b1[m][r] = __builtin_inff(); b2[m][r] = __builtin_inff(); i1[m][r] = 0; }

    stage_tile(cbh, cbl, csqg, &sm[0][0], 0, wid, lane);
    __syncthreads();   // drains vmcnt(0): tile 0 resident
    int cur = 0;
    for (int kt = 0; kt < K_CB; kt += 128) {
        if (kt + 128 < K_CB)
            stage_tile(cbh, cbl, csqg, &sm[cur ^ 1][0], kt + 128, wid, lane);
        const unsigned char* bhp = &sm[cur][0];
        const unsigned char* blp = &sm[cur][16384];
        const float* cs_l = (const float*)&sm[cur][32768];
        #pragma unroll 2
        for (int c = 0; c < 8; ++c) {
            const int brow = c * 16 + (lane & 15);
            short8 bh0 = ldfrag(bhp, brow, lane, 0), bh1 = ldfrag(bhp, brow, lane, 1);
            short8 bl0 = ldfrag(blp, brow, lane, 0), bl1 = ldfrag(blp, brow, lane, 1);
            const float cs = cs_l[c * 16 + (lane & 15)];
            const int idx = kt + c * 16 + (lane & 15);
            #pragma unroll
            for (int m = 0; m < 2; ++m) {
                f32x4 a0 = {0.f, 0.f, 0.f, 0.f}, a1 = {0.f, 0.f, 0.f, 0.f};
                a0 = MFMA(ah[m][0], bh0, a0);
                a1 = MFMA(ah[m][1], bh1, a1);
                a0 = MFMA(al[m][0], bh0, a0);   // xl*ch
                a1 = MFMA(al[m][1], bh1, a1);
                a0 = MFMA(ah[m][0], bl0, a0);   // xh*cl
                a1 = MFMA(ah[m][1], bl1, a1);
                #pragma unroll
                for (int r = 0; r < 4; ++r) {
                    const float d = fmaf(a0[r] + a1[r], -2.f, cs);
                    const bool lt = d < b1[m][r];
                    b2[m][r] = fminf(b2[m][r], lt ? b1[m][r] : d);
                    b1[m][r] = lt ? d : b1[m][r];
                    i1[m][r] = lt ? idx : i1[m][r];
                }
            }
        }
        __syncthreads();   // drains next-tile staging loads; all waves done with cur
        cur ^= 1;
    }

    // cross-lane argmin (16 lanes share a row group), first-index tie-break
    #pragma unroll
    for (int m = 0; m < 2; ++m)
        #pragma unroll
        for (int r = 0; r < 4; ++r) {
            float v1 = b1[m][r], v2 = b2[m][r]; int j1 = i1[m][r];
            #pragma unroll
            for (int msk = 1; msk < 16; msk <<= 1) {
                const float ov1 = __shfl_xor(v1, msk);
                const int   oj1 = __shfl_xor(j1, msk);
                const float ov2 = __shfl_xor(v2, msk);
                const bool take = (ov1 < v1) || (ov1 == v1 && oj1 < j1);
                const float nv2 = fminf(take ? v1 : v2, take ? ov2 : ov1);
                v1 = take ? ov1 : v1; j1 = take ? oj1 : j1; v2 = nv2;
            }
            if ((lane & 15) == 0) {
                const int row = n0 + wbase + m * 16 + (lane >> 4) * 4 + r;
                besti[row] = j1;
                if (v2 - v1 < EPS_MARGIN) {
                    const int p = atomicAdd(counter, 1);
                    list[p] = row;
                }
            }
        }
}

// ---- repair: exact fp32 argmin for flagged rows (one block per row) ----
__global__ __launch_bounds__(256)
void repair_kernel(const float* __restrict__ z, const float* __restrict__ cb,
                   const float* __restrict__ csq, const int* __restrict__ list,
                   const int* __restrict__ counter, int* __restrict__ besti) {
    __shared__ float xs[64];
    __shared__ float rv[4];
    __shared__ int   ri[4];
    const int cnt = counter[0];
    const int t = threadIdx.x;
    for (int e = blockIdx.x; e < cnt; e += gridDim.x) {
        const int row = list[e];
        __syncthreads();
        if (t < 64) xs[t] = z[(size_t)row * D_DIM + t];
        __syncthreads();
        float bv = __builtin_inff(); int bi = 0x7fffffff;
        for (int k = t; k < K_CB; k += 256) {
            const float4* cr = (const float4*)(cb + (size_t)k * D_DIM);
            float dot = 0.f;
            #pragma unroll
            for (int i = 0; i < 16; ++i) {
                float4 v = cr[i];
                dot = fmaf(v.x, xs[i * 4 + 0], dot);
                dot = fmaf(v.y, xs[i * 4 + 1], dot);
                dot = fmaf(v.z, xs[i * 4 + 2], dot);
                dot = fmaf(v.w, xs[i * 4 + 3], dot);
            }
            const float d = fmaf(dot, -2.f, csq[k]);
            if (d < bv) { bv = d; bi = k; }
        }
        #pragma unroll
        for (int msk = 1; msk < 64; msk <<= 1) {
            const float ov = __shfl_xor(bv, msk);
            const int   oi = __shfl_xor(bi, msk);
            if (ov < bv || (ov == bv && oi < bi)) { bv = ov; bi = oi; }
        }
        if ((t & 63) == 0) { rv[t >> 6] = bv; ri[t >> 6] = bi; }
        __syncthreads();
        if (t == 0) {
            float fb = rv[0]; int fi = ri[0];
            #pragma unroll
            for (int w = 1; w < 4; ++w)
                if (rv[w] < fb || (rv[w] == fb && ri[w] < fi)) { fb = rv[w]; fi = ri[w]; }
            besti[row] = fi;
        }
        __syncthreads();
    }
}

// ---- gather winners, write both output slices ----
__global__ __launch_bounds__(256)
void gather_kernel(const float* __restrict__ cb, const int* __restrict__ besti,
                   float* __restrict__ out) {
    const int id  = blockIdx.x * 256 + threadIdx.x;
    const int row = id >> 4, c4 = id & 15;
    const int k = besti[row];
    const float4 v = ((const float4*)cb)[(size_t)k * 16 + c4];
    ((float4*)out)[(size_t)row * 16 + c4] = v;
    ((float4*)out)[(size_t)N_ROWS * 16 + (size_t)row * 16 + c4] = v;
}

extern "C" void kernel_launch(void* const* d_in, const int* in_sizes, int n_in,
                              void* d_out, int out_size, void* d_ws, size_t ws_size,
                              hipStream_t stream) {
    const float* z  = (const float*)d_in[0];
    const float* cb = (const float*)d_in[1];
    float* out = (float*)d_out;
    unsigned char* ws = (unsigned char*)d_ws;

    int*   counter = (int*)(ws + CTR_OFF);
    float* csq     = (float*)(ws + CSQ_OFF);
    unsigned char* cbh = ws + CBH_OFF;
    unsigned char* cbl = ws + CBL_OFF;
    int* besti = (int*)(ws + BESTI_OFF);
    int* list  = (int*)(ws + LIST_OFF);

    prep_csq<<<K_CB / 256, 256, 0, stream>>>(cb, csq);
    prep_split<<<(K_CB * 8) / 256, 256, 0, stream>>>(cb, cbh, cbl);
    init_counter<<<1, 64, 0, stream>>>(counter);
    vq_main_mfma<<<N_ROWS / 128, 256, 0, stream>>>(z, cbh, cbl, csq, besti, list, counter);
    repair_kernel<<<512, 256, 0, stream>>>(z, cb, csq, list, counter, besti);
    gather_kernel<<<(N_ROWS * 16) / 256, 256, 0, stream>>>(cb, besti, out);
}

// Round 3
// 287.616 us; speedup vs baseline: 3.2164x; 1.7132x over previous
//
#include <hip/hip_runtime.h>

typedef __attribute__((ext_vector_type(8))) short short8;   // 8 x bf16 fragment
typedef __attribute__((ext_vector_type(4))) float f32x4;

constexpr int N_ROWS = 131072;
constexpr int K_CB   = 4096;
constexpr int D_DIM  = 64;
constexpr float EPS_MARGIN = 2.0e-3f;

// ---- ws layout (bytes) ----
constexpr size_t CTR_OFF   = 0;        // int counter
constexpr size_t CSQ_OFF   = 64;       // 4096 f32
constexpr size_t CBH_OFF   = 16512;    // 4096*64 bf16, pre-swizzled   (512 KB)
constexpr size_t CBL_OFF   = CBH_OFF + 524288;
constexpr size_t BESTI_OFF = CBL_OFF + 524288;   // N int
constexpr size_t LIST_OFF  = BESTI_OFF + 524288; // N int

#define MFMA(a, b, c) __builtin_amdgcn_mfma_f32_16x16x32_bf16((a), (b), (c), 0, 0, 0)

__device__ __forceinline__ unsigned short f2bf(float f) {
    unsigned int u = __builtin_bit_cast(unsigned int, f);
    u = (u + 0x7fffu + ((u >> 16) & 1u)) >> 16;   // RTNE
    return (unsigned short)u;
}
__device__ __forceinline__ float bf2f(unsigned short h) {
    return __builtin_bit_cast(float, ((unsigned int)h) << 16);
}

// swizzled 16B fragment read: row*128B row-major tile, slot XOR (row&7)
__device__ __forceinline__ short8 ldfrag(const unsigned char* smbase, int row, int lane, int ks) {
    const int slot = (((lane >> 4) + ks * 4) ^ (lane & 7));
    uint4 v = *(const uint4*)(smbase + row * 128 + slot * 16);
    return __builtin_bit_cast(short8, v);
}

// ---- prep: codebook squared norms (exact fp32) ----
__global__ __launch_bounds__(256)
void prep_csq(const float* __restrict__ cb, float* __restrict__ csq) {
    const int k = blockIdx.x * 256 + threadIdx.x;
    const float4* row = (const float4*)(cb + (size_t)k * D_DIM);
    float s = 0.f;
    #pragma unroll
    for (int i = 0; i < 16; ++i) {
        float4 v = row[i];
        s = fmaf(v.x, v.x, s); s = fmaf(v.y, v.y, s);
        s = fmaf(v.z, v.z, s); s = fmaf(v.w, v.w, s);
    }
    csq[k] = s;
}

// ---- prep: split cb into hi/lo bf16 planes, PRE-SWIZZLED (slot ^= row&7) ----
__global__ __launch_bounds__(256)
void prep_split(const float* __restrict__ cb, unsigned char* __restrict__ cbh,
                unsigned char* __restrict__ cbl) {
    const int id  = blockIdx.x * 256 + threadIdx.x;   // 32768 = 4096 rows * 8 slots
    const int row = id >> 3, s = id & 7;
    const float4* src = (const float4*)(cb + (size_t)row * D_DIM + s * 8);
    float4 v0 = src[0], v1 = src[1];
    float f[8] = {v0.x, v0.y, v0.z, v0.w, v1.x, v1.y, v1.z, v1.w};
    unsigned int hw[4], lw[4];
    #pragma unroll
    for (int i = 0; i < 4; ++i) {
        unsigned short h0 = f2bf(f[2*i]),     l0 = f2bf(f[2*i]     - bf2f(h0));
        unsigned short h1 = f2bf(f[2*i + 1]), l1 = f2bf(f[2*i + 1] - bf2f(h1));
        hw[i] = (unsigned int)h0 | ((unsigned int)h1 << 16);
        lw[i] = (unsigned int)l0 | ((unsigned int)l1 << 16);
    }
    const int slot = s ^ (row & 7);
    *(uint4*)(cbh + (size_t)row * 128 + slot * 16) = make_uint4(hw[0], hw[1], hw[2], hw[3]);
    *(uint4*)(cbl + (size_t)row * 128 + slot * 16) = make_uint4(lw[0], lw[1], lw[2], lw[3]);
}

__global__ void init_counter(int* counter) { if (threadIdx.x == 0) *counter = 0; }

// ---- stage one 128-code tile (hi 16KB + lo 16KB + csq 512B) via global_load_lds ----
__device__ __forceinline__ void stage_tile(const unsigned char* __restrict__ cbh,
                                           const unsigned char* __restrict__ cbl,
                                           const float* __restrict__ csqg,
                                           unsigned char* sm, int kt, int wid, int lane) {
    const unsigned char* sh = cbh + (size_t)kt * 128;
    const unsigned char* sl = cbl + (size_t)kt * 128;
    #pragma unroll
    for (int p = 0; p < 4; ++p) {
        const int chunk = wid * 4 + p;
        __builtin_amdgcn_global_load_lds(
            (const __attribute__((address_space(1))) void*)(sh + chunk * 1024 + lane * 16),
            (__attribute__((address_space(3))) void*)(sm + chunk * 1024), 16, 0, 0);
    }
    #pragma unroll
    for (int p = 0; p < 4; ++p) {
        const int chunk = wid * 4 + p;
        __builtin_amdgcn_global_load_lds(
            (const __attribute__((address_space(1))) void*)(sl + chunk * 1024 + lane * 16),
            (__attribute__((address_space(3))) void*)(sm + 16384 + chunk * 1024), 16, 0, 0);
    }
    if (wid < 2) {
        __builtin_amdgcn_global_load_lds(
            (const __attribute__((address_space(1))) void*)(csqg + kt + wid * 64 + lane),
            (__attribute__((address_space(3))) void*)(sm + 32768 + wid * 256), 4, 0, 0);
    }
}

// ---- main: 4-term split-bf16 MFMA distances + argmin + fused gather ----
__global__ __launch_bounds__(256, 2)
void vq_main_mfma(const float* __restrict__ z,
                  const float* __restrict__ cb,
                  const unsigned char* __restrict__ cbh,
                  const unsigned char* __restrict__ cbl,
                  const float* __restrict__ csqg,
                  int* __restrict__ besti, int* __restrict__ list,
                  int* __restrict__ counter, float* __restrict__ out) {
    __shared__ __align__(16) unsigned char sm[2][33792];   // hi 16K | lo 16K | csq 512B
    const int t = threadIdx.x, lane = t & 63, wid = t >> 6;
    const int n0 = blockIdx.x * 128;
    const int wbase = wid * 32;

    // stage A tile (128 rows of z) hi/lo swizzled into sm[0]
    #pragma unroll
    for (int p = 0; p < 4; ++p) {
        const int id = t + p * 256;          // 1024 = 128 rows * 8 slots
        const int row = id >> 3, s = id & 7;
        const float4* src = (const float4*)(z + (size_t)(n0 + row) * D_DIM + s * 8);
        float4 v0 = src[0], v1 = src[1];
        float f[8] = {v0.x, v0.y, v0.z, v0.w, v1.x, v1.y, v1.z, v1.w};
        unsigned int hw[4], lw[4];
        #pragma unroll
        for (int i = 0; i < 4; ++i) {
            unsigned short h0 = f2bf(f[2*i]),     l0 = f2bf(f[2*i]     - bf2f(h0));
            unsigned short h1 = f2bf(f[2*i + 1]), l1 = f2bf(f[2*i + 1] - bf2f(h1));
            hw[i] = (unsigned int)h0 | ((unsigned int)h1 << 16);
            lw[i] = (unsigned int)l0 | ((unsigned int)l1 << 16);
        }
        const int slot = s ^ (row & 7);
        *(uint4*)(&sm[0][row * 128 + slot * 16])         = make_uint4(hw[0], hw[1], hw[2], hw[3]);
        *(uint4*)(&sm[0][16384 + row * 128 + slot * 16]) = make_uint4(lw[0], lw[1], lw[2], lw[3]);
    }
    __syncthreads();

    short8 ah[2][2], al[2][2];
    #pragma unroll
    for (int m = 0; m < 2; ++m)
        #pragma unroll
        for (int ks = 0; ks < 2; ++ks) {
            const int row = wbase + m * 16 + (lane & 15);
            ah[m][ks] = ldfrag(&sm[0][0],     row, lane, ks);
            al[m][ks] = ldfrag(&sm[0][16384], row, lane, ks);
        }
    __syncthreads();   // everyone done reading A before B staging overwrites

    float b1[2][4], b2[2][4]; int i1[2][4];
    #pragma unroll
    for (int m = 0; m < 2; ++m)
        #pragma unroll
        for (int r = 0; r < 4; ++r) { b1[m][r] = __builtin_inff(); b2[m][r] = __builtin_inff(); i1[m][r] = 0; }

    stage_tile(cbh, cbl, csqg, &sm[0][0], 0, wid, lane);
    __syncthreads();   // drains vmcnt(0): tile 0 resident
    int cur = 0;
    for (int kt = 0; kt < K_CB; kt += 128) {
        if (kt + 128 < K_CB)
            stage_tile(cbh, cbl, csqg, &sm[cur ^ 1][0], kt + 128, wid, lane);
        const unsigned char* bhp = &sm[cur][0];
        const unsigned char* blp = &sm[cur][16384];
        const float* cs_l = (const float*)&sm[cur][32768];
        #pragma unroll 2
        for (int c = 0; c < 8; ++c) {
            const int brow = c * 16 + (lane & 15);
            short8 bh0 = ldfrag(bhp, brow, lane, 0), bh1 = ldfrag(bhp, brow, lane, 1);
            short8 bl0 = ldfrag(blp, brow, lane, 0), bl1 = ldfrag(blp, brow, lane, 1);
            const float cs = cs_l[c * 16 + (lane & 15)];
            const int idx = kt + c * 16 + (lane & 15);
            #pragma unroll
            for (int m = 0; m < 2; ++m) {
                f32x4 a0 = {0.f, 0.f, 0.f, 0.f}, a1 = {0.f, 0.f, 0.f, 0.f};
                a0 = MFMA(ah[m][0], bh0, a0);
                a1 = MFMA(ah[m][1], bh1, a1);
                a0 = MFMA(al[m][0], bh0, a0);   // xl*ch
                a1 = MFMA(al[m][1], bh1, a1);
                a0 = MFMA(ah[m][0], bl0, a0);   // xh*cl
                a1 = MFMA(ah[m][1], bl1, a1);
                a0 = MFMA(al[m][0], bl0, a0);   // xl*cl
                a1 = MFMA(al[m][1], bl1, a1);
                #pragma unroll
                for (int r = 0; r < 4; ++r) {
                    const float d = fmaf(a0[r] + a1[r], -2.f, cs);
                    const bool lt = d < b1[m][r];
                    b2[m][r] = fminf(b2[m][r], lt ? b1[m][r] : d);
                    b1[m][r] = lt ? d : b1[m][r];
                    i1[m][r] = lt ? idx : i1[m][r];
                }
            }
        }
        __syncthreads();   // drains next-tile staging loads; all waves done with cur
        cur ^= 1;
    }

    // cross-lane argmin (16 lanes share a row group), first-index tie-break
    int* bidx_lds = (int*)&sm[0][0];
    #pragma unroll
    for (int m = 0; m < 2; ++m)
        #pragma unroll
        for (int r = 0; r < 4; ++r) {
            float v1 = b1[m][r], v2 = b2[m][r]; int j1 = i1[m][r];
            #pragma unroll
            for (int msk = 1; msk < 16; msk <<= 1) {
                const float ov1 = __shfl_xor(v1, msk);
                const int   oj1 = __shfl_xor(j1, msk);
                const float ov2 = __shfl_xor(v2, msk);
                const bool take = (ov1 < v1) || (ov1 == v1 && oj1 < j1);
                const float nv2 = fminf(take ? v1 : v2, take ? ov2 : ov1);
                v1 = take ? ov1 : v1; j1 = take ? oj1 : j1; v2 = nv2;
            }
            if ((lane & 15) == 0) {
                const int rloc = wbase + m * 16 + (lane >> 4) * 4 + r;
                const int row = n0 + rloc;
                besti[row] = j1;
                bidx_lds[rloc] = j1;
                if (v2 - v1 < EPS_MARGIN) {
                    const int p = atomicAdd(counter, 1);
                    list[p] = row;
                }
            }
        }
    __syncthreads();

    // fused gather: write both output slices for this block's 128 rows
    const float4* cb4 = (const float4*)cb;
    float4* out4 = (float4*)out;
    #pragma unroll
    for (int p = 0; p < 8; ++p) {
        const int id  = t + p * 256;       // 2048 = 128 rows * 16 chunks
        const int row = id >> 4, c4 = id & 15;
        const int k = bidx_lds[row];
        const float4 v = cb4[(size_t)k * 16 + c4];
        out4[(size_t)(n0 + row) * 16 + c4] = v;
        out4[(size_t)N_ROWS * 16 + (size_t)(n0 + row) * 16 + c4] = v;
    }
}

// ---- repair: exact fp32 argmin for flagged rows; also rewrites their outputs ----
__global__ __launch_bounds__(256)
void repair_kernel(const float* __restrict__ z, const float* __restrict__ cb,
                   const float* __restrict__ csq, const int* __restrict__ list,
                   const int* __restrict__ counter, int* __restrict__ besti,
                   float* __restrict__ out) {
    __shared__ float xs[64];
    __shared__ float rv[4];
    __shared__ int   ri[4];
    __shared__ int   fi_s;
    const int cnt = counter[0];
    const int t = threadIdx.x;
    for (int e = blockIdx.x; e < cnt; e += gridDim.x) {
        const int row = list[e];
        __syncthreads();
        if (t < 64) xs[t] = z[(size_t)row * D_DIM + t];
        __syncthreads();
        float bv = __builtin_inff(); int bi = 0x7fffffff;
        for (int k = t; k < K_CB; k += 256) {
            const float4* cr = (const float4*)(cb + (size_t)k * D_DIM);
            float dot = 0.f;
            #pragma unroll
            for (int i = 0; i < 16; ++i) {
                float4 v = cr[i];
                dot = fmaf(v.x, xs[i * 4 + 0], dot);
                dot = fmaf(v.y, xs[i * 4 + 1], dot);
                dot = fmaf(v.z, xs[i * 4 + 2], dot);
                dot = fmaf(v.w, xs[i * 4 + 3], dot);
            }
            const float d = fmaf(dot, -2.f, csq[k]);
            if (d < bv) { bv = d; bi = k; }
        }
        #pragma unroll
        for (int msk = 1; msk < 64; msk <<= 1) {
            const float ov = __shfl_xor(bv, msk);
            const int   oi = __shfl_xor(bi, msk);
            if (ov < bv || (ov == bv && oi < bi)) { bv = ov; bi = oi; }
        }
        if ((t & 63) == 0) { rv[t >> 6] = bv; ri[t >> 6] = bi; }
        __syncthreads();
        if (t == 0) {
            float fb = rv[0]; int fi = ri[0];
            #pragma unroll
            for (int w = 1; w < 4; ++w)
                if (rv[w] < fb || (rv[w] == fb && ri[w] < fi)) { fb = rv[w]; fi = ri[w]; }
            besti[row] = fi;
            fi_s = fi;
        }
        __syncthreads();
        if (t < 32) {
            const int dest = t >> 4, c4 = t & 15;
            const float4 v = ((const float4*)cb)[(size_t)fi_s * 16 + c4];
            float4* dst = (float4*)out + (size_t)dest * N_ROWS * 16 + (size_t)row * 16 + c4;
            *dst = v;
        }
        __syncthreads();
    }
}

extern "C" void kernel_launch(void* const* d_in, const int* in_sizes, int n_in,
                              void* d_out, int out_size, void* d_ws, size_t ws_size,
                              hipStream_t stream) {
    const float* z  = (const float*)d_in[0];
    const float* cb = (const float*)d_in[1];
    float* out = (float*)d_out;
    unsigned char* ws = (unsigned char*)d_ws;

    int*   counter = (int*)(ws + CTR_OFF);
    float* csq     = (float*)(ws + CSQ_OFF);
    unsigned char* cbh = ws + CBH_OFF;
    unsigned char* cbl = ws + CBL_OFF;
    int* besti = (int*)(ws + BESTI_OFF);
    int* list  = (int*)(ws + LIST_OFF);

    prep_csq<<<K_CB / 256, 256, 0, stream>>>(cb, csq);
    prep_split<<<(K_CB * 8) / 256, 256, 0, stream>>>(cb, cbh, cbl);
    init_counter<<<1, 64, 0, stream>>>(counter);
    vq_main_mfma<<<N_ROWS / 128, 256, 0, stream>>>(z, cb, cbh, cbl, csq, besti, list, counter, out);
    repair_kernel<<<1024, 256, 0, stream>>>(z, cb, csq, list, counter, besti, out);
}

// Round 4
// 255.901 us; speedup vs baseline: 3.6150x; 1.1239x over previous
//
#include <hip/hip_runtime.h>

typedef __attribute__((ext_vector_type(8))) short short8;   // 8 x bf16 fragment
typedef __attribute__((ext_vector_type(4))) float f32x4;

constexpr int N_ROWS = 131072;
constexpr int K_CB   = 4096;
constexpr int D_DIM  = 64;
constexpr float EPS_MARGIN = 2.5e-3f;

// ---- ws layout (bytes) ----
constexpr size_t CTR_OFF   = 0;        // int counter
constexpr size_t CSQ_OFF   = 64;       // 4096 f32
constexpr size_t CBH_OFF   = 16512;    // 4096*64 bf16, pre-swizzled   (512 KB)
constexpr size_t CBL_OFF   = CBH_OFF + 524288;
constexpr size_t LIST_OFF  = CBL_OFF + 524288;   // N int

#define MFMA(a, b, c) __builtin_amdgcn_mfma_f32_16x16x32_bf16((a), (b), (c), 0, 0, 0)

__device__ __forceinline__ unsigned short f2bf(float f) {
    unsigned int u = __builtin_bit_cast(unsigned int, f);
    u = (u + 0x7fffu + ((u >> 16) & 1u)) >> 16;   // RTNE
    return (unsigned short)u;
}
__device__ __forceinline__ float bf2f(unsigned short h) {
    return __builtin_bit_cast(float, ((unsigned int)h) << 16);
}

// swizzled 16B fragment read: row*128B row-major tile, slot XOR (row&7)
__device__ __forceinline__ short8 ldfrag(const unsigned char* smbase, int row, int lane, int ks) {
    const int slot = (((lane >> 4) + ks * 4) ^ (lane & 7));
    uint4 v = *(const uint4*)(smbase + row * 128 + slot * 16);
    return __builtin_bit_cast(short8, v);
}

// ---- prep: codebook squared norms (exact fp32) ----
__global__ __launch_bounds__(256)
void prep_csq(const float* __restrict__ cb, float* __restrict__ csq) {
    const int k = blockIdx.x * 256 + threadIdx.x;
    const float4* row = (const float4*)(cb + (size_t)k * D_DIM);
    float s = 0.f;
    #pragma unroll
    for (int i = 0; i < 16; ++i) {
        float4 v = row[i];
        s = fmaf(v.x, v.x, s); s = fmaf(v.y, v.y, s);
        s = fmaf(v.z, v.z, s); s = fmaf(v.w, v.w, s);
    }
    csq[k] = s;
}

// ---- prep: split cb into hi/lo bf16 planes, PRE-SWIZZLED (slot ^= row&7) ----
__global__ __launch_bounds__(256)
void prep_split(const float* __restrict__ cb, unsigned char* __restrict__ cbh,
                unsigned char* __restrict__ cbl) {
    const int id  = blockIdx.x * 256 + threadIdx.x;   // 32768 = 4096 rows * 8 slots
    const int row = id >> 3, s = id & 7;
    const float4* src = (const float4*)(cb + (size_t)row * D_DIM + s * 8);
    float4 v0 = src[0], v1 = src[1];
    float f[8] = {v0.x, v0.y, v0.z, v0.w, v1.x, v1.y, v1.z, v1.w};
    unsigned int hw[4], lw[4];
    #pragma unroll
    for (int i = 0; i < 4; ++i) {
        unsigned short h0 = f2bf(f[2*i]),     l0 = f2bf(f[2*i]     - bf2f(h0));
        unsigned short h1 = f2bf(f[2*i + 1]), l1 = f2bf(f[2*i + 1] - bf2f(h1));
        hw[i] = (unsigned int)h0 | ((unsigned int)h1 << 16);
        lw[i] = (unsigned int)l0 | ((unsigned int)l1 << 16);
    }
    const int slot = s ^ (row & 7);
    *(uint4*)(cbh + (size_t)row * 128 + slot * 16) = make_uint4(hw[0], hw[1], hw[2], hw[3]);
    *(uint4*)(cbl + (size_t)row * 128 + slot * 16) = make_uint4(lw[0], lw[1], lw[2], lw[3]);
}

__global__ void init_counter(int* counter) { if (threadIdx.x == 0) *counter = 0; }

// ---- stage one 64-code tile (hi 8KB + lo 8KB + csq 256B) via global_load_lds ----
__device__ __forceinline__ void stage_tile(const unsigned char* __restrict__ cbh,
                                           const unsigned char* __restrict__ cbl,
                                           const float* __restrict__ csqg,
                                           unsigned char* sm, int kt, int wid, int lane) {
    const unsigned char* sh = cbh + (size_t)kt * 128;
    const unsigned char* sl = cbl + (size_t)kt * 128;
    #pragma unroll
    for (int p = 0; p < 2; ++p) {
        const int chunk = wid * 2 + p;
        __builtin_amdgcn_global_load_lds(
            (const __attribute__((address_space(1))) void*)(sh + chunk * 1024 + lane * 16),
            (__attribute__((address_space(3))) void*)(sm + chunk * 1024), 16, 0, 0);
    }
    #pragma unroll
    for (int p = 0; p < 2; ++p) {
        const int chunk = wid * 2 + p;
        __builtin_amdgcn_global_load_lds(
            (const __attribute__((address_space(1))) void*)(sl + chunk * 1024 + lane * 16),
            (__attribute__((address_space(3))) void*)(sm + 8192 + chunk * 1024), 16, 0, 0);
    }
    if (wid == 0) {
        __builtin_amdgcn_global_load_lds(
            (const __attribute__((address_space(1))) void*)(csqg + kt + lane),
            (__attribute__((address_space(3))) void*)(sm + 16384), 4, 0, 0);
    }
}

// ---- main: 3-term split-bf16 MFMA distances + argmin + fused gather ----
__global__ __launch_bounds__(256, 4)
void vq_main_mfma(const float* __restrict__ z,
                  const float* __restrict__ cb,
                  const unsigned char* __restrict__ cbh,
                  const unsigned char* __restrict__ cbl,
                  const float* __restrict__ csqg,
                  int* __restrict__ list,
                  int* __restrict__ counter, float* __restrict__ out) {
    // per buffer: hi 8K | lo 8K | csq 256B  -> 16640 B; two buffers = 33280 B.
    // A-staging (hi 16K @0, lo 16K @16384) transiently spans both buffers.
    __shared__ __align__(16) unsigned char sm[2][16640];
    unsigned char* smf = &sm[0][0];
    const int t = threadIdx.x, lane = t & 63, wid = t >> 6;
    const int n0 = blockIdx.x * 128;
    const int wbase = wid * 32;

    // stage A tile (128 rows of z) hi/lo swizzled
    #pragma unroll
    for (int p = 0; p < 4; ++p) {
        const int id = t + p * 256;          // 1024 = 128 rows * 8 slots
        const int row = id >> 3, s = id & 7;
        const float4* src = (const float4*)(z + (size_t)(n0 + row) * D_DIM + s * 8);
        float4 v0 = src[0], v1 = src[1];
        float f[8] = {v0.x, v0.y, v0.z, v0.w, v1.x, v1.y, v1.z, v1.w};
        unsigned int hw[4], lw[4];
        #pragma unroll
        for (int i = 0; i < 4; ++i) {
            unsigned short h0 = f2bf(f[2*i]),     l0 = f2bf(f[2*i]     - bf2f(h0));
            unsigned short h1 = f2bf(f[2*i + 1]), l1 = f2bf(f[2*i + 1] - bf2f(h1));
            hw[i] = (unsigned int)h0 | ((unsigned int)h1 << 16);
            lw[i] = (unsigned int)l0 | ((unsigned int)l1 << 16);
        }
        const int slot = s ^ (row & 7);
        *(uint4*)(smf + row * 128 + slot * 16)         = make_uint4(hw[0], hw[1], hw[2], hw[3]);
        *(uint4*)(smf + 16384 + row * 128 + slot * 16) = make_uint4(lw[0], lw[1], lw[2], lw[3]);
    }
    __syncthreads();

    short8 ah[2][2], al[2][2];
    #pragma unroll
    for (int m = 0; m < 2; ++m)
        #pragma unroll
        for (int ks = 0; ks < 2; ++ks) {
            const int row = wbase + m * 16 + (lane & 15);
            ah[m][ks] = ldfrag(smf,         row, lane, ks);
            al[m][ks] = ldfrag(smf + 16384, row, lane, ks);
        }
    __syncthreads();   // everyone done reading A before B staging overwrites

    float b1[2][4], b2[2][4]; int i1[2][4];
    #pragma unroll
    for (int m = 0; m < 2; ++m)
        #pragma unroll
        for (int r = 0; r < 4; ++r) { b1[m][r] = __builtin_inff(); b2[m][r] = __builtin_inff(); i1[m][r] = 0; }

    stage_tile(cbh, cbl, csqg, &sm[0][0], 0, wid, lane);
    __syncthreads();   // drains vmcnt(0): tile 0 resident
    int cur = 0;
    for (int kt = 0; kt < K_CB; kt += 64) {
        if (kt + 64 < K_CB)
            stage_tile(cbh, cbl, csqg, &sm[cur ^ 1][0], kt + 64, wid, lane);
        const unsigned char* bhp = &sm[cur][0];
        const unsigned char* blp = &sm[cur][8192];
        const float* cs_l = (const float*)&sm[cur][16384];
        #pragma unroll 2
        for (int c = 0; c < 4; ++c) {
            const int brow = c * 16 + (lane & 15);
            short8 bh0 = ldfrag(bhp, brow, lane, 0), bh1 = ldfrag(bhp, brow, lane, 1);
            short8 bl0 = ldfrag(blp, brow, lane, 0), bl1 = ldfrag(blp, brow, lane, 1);
            const float cs = cs_l[c * 16 + (lane & 15)];
            const int idx = kt + c * 16 + (lane & 15);
            #pragma unroll
            for (int m = 0; m < 2; ++m) {
                f32x4 a0 = {0.f, 0.f, 0.f, 0.f}, a1 = {0.f, 0.f, 0.f, 0.f};
                a0 = MFMA(ah[m][0], bh0, a0);
                a1 = MFMA(ah[m][1], bh1, a1);
                a0 = MFMA(al[m][0], bh0, a0);   // xl*ch
                a1 = MFMA(al[m][1], bh1, a1);
                a0 = MFMA(ah[m][0], bl0, a0);   // xh*cl
                a1 = MFMA(ah[m][1], bl1, a1);
                #pragma unroll
                for (int r = 0; r < 4; ++r) {
                    const float d = fmaf(a0[r] + a1[r], -2.f, cs);
                    const bool lt = d < b1[m][r];
                    b2[m][r] = fminf(b2[m][r], lt ? b1[m][r] : d);
                    b1[m][r] = lt ? d : b1[m][r];
                    i1[m][r] = lt ? idx : i1[m][r];
                }
            }
        }
        __syncthreads();   // drains next-tile staging loads; all waves done with cur
        cur ^= 1;
    }

    // cross-lane argmin (16 lanes share a row group), first-index tie-break
    int* bidx_lds = (int*)&sm[0][0];
    #pragma unroll
    for (int m = 0; m < 2; ++m)
        #pragma unroll
        for (int r = 0; r < 4; ++r) {
            float v1 = b1[m][r], v2 = b2[m][r]; int j1 = i1[m][r];
            #pragma unroll
            for (int msk = 1; msk < 16; msk <<= 1) {
                const float ov1 = __shfl_xor(v1, msk);
                const int   oj1 = __shfl_xor(j1, msk);
                const float ov2 = __shfl_xor(v2, msk);
                const bool take = (ov1 < v1) || (ov1 == v1 && oj1 < j1);
                const float nv2 = fminf(take ? v1 : v2, take ? ov2 : ov1);
                v1 = take ? ov1 : v1; j1 = take ? oj1 : j1; v2 = nv2;
            }
            if ((lane & 15) == 0) {
                const int rloc = wbase + m * 16 + (lane >> 4) * 4 + r;
                bidx_lds[rloc] = j1;
                if (v2 - v1 < EPS_MARGIN) {
                    const int p = atomicAdd(counter, 1);
                    list[p] = n0 + rloc;
                }
            }
        }
    __syncthreads();

    // fused gather: write both output slices for this block's 128 rows
    const float4* cb4 = (const float4*)cb;
    float4* out4 = (float4*)out;
    #pragma unroll
    for (int p = 0; p < 8; ++p) {
        const int id  = t + p * 256;       // 2048 = 128 rows * 16 chunks
        const int row = id >> 4, c4 = id & 15;
        const int k = bidx_lds[row];
        const float4 v = cb4[(size_t)k * 16 + c4];
        out4[(size_t)(n0 + row) * 16 + c4] = v;
        out4[(size_t)N_ROWS * 16 + (size_t)(n0 + row) * 16 + c4] = v;
    }
}

// ---- repair: exact fp32 argmin for flagged rows; rewrites their outputs ----
__global__ __launch_bounds__(256)
void repair_kernel(const float* __restrict__ z, const float* __restrict__ cb,
                   const float* __restrict__ csq, const int* __restrict__ list,
                   const int* __restrict__ counter, float* __restrict__ out) {
    __shared__ float xs[64];
    __shared__ float rv[4];
    __shared__ int   ri[4];
    __shared__ int   fi_s;
    const int cnt = counter[0];
    const int t = threadIdx.x;
    for (int e = blockIdx.x; e < cnt; e += gridDim.x) {
        const int row = list[e];
        __syncthreads();
        if (t < 64) xs[t] = z[(size_t)row * D_DIM + t];
        __syncthreads();
        float bv = __builtin_inff(); int bi = 0x7fffffff;
        for (int k = t; k < K_CB; k += 256) {
            const float4* cr = (const float4*)(cb + (size_t)k * D_DIM);
            float dot = 0.f;
            #pragma unroll
            for (int i = 0; i < 16; ++i) {
                float4 v = cr[i];
                dot = fmaf(v.x, xs[i * 4 + 0], dot);
                dot = fmaf(v.y, xs[i * 4 + 1], dot);
                dot = fmaf(v.z, xs[i * 4 + 2], dot);
                dot = fmaf(v.w, xs[i * 4 + 3], dot);
            }
            const float d = fmaf(dot, -2.f, csq[k]);
            if (d < bv) { bv = d; bi = k; }
        }
        #pragma unroll
        for (int msk = 1; msk < 64; msk <<= 1) {
            const float ov = __shfl_xor(bv, msk);
            const int   oi = __shfl_xor(bi, msk);
            if (ov < bv || (ov == bv && oi < bi)) { bv = ov; bi = oi; }
        }
        if ((t & 63) == 0) { rv[t >> 6] = bv; ri[t >> 6] = bi; }
        __syncthreads();
        if (t == 0) {
            float fb = rv[0]; int fi = ri[0];
            #pragma unroll
            for (int w = 1; w < 4; ++w)
                if (rv[w] < fb || (rv[w] == fb && ri[w] < fi)) { fb = rv[w]; fi = ri[w]; }
            fi_s = fi;
        }
        __syncthreads();
        if (t < 32) {
            const int dest = t >> 4, c4 = t & 15;
            const float4 v = ((const float4*)cb)[(size_t)fi_s * 16 + c4];
            float4* dst = (float4*)out + (size_t)dest * N_ROWS * 16 + (size_t)row * 16 + c4;
            *dst = v;
        }
        __syncthreads();
    }
}

extern "C" void kernel_launch(void* const* d_in, const int* in_sizes, int n_in,
                              void* d_out, int out_size, void* d_ws, size_t ws_size,
                              hipStream_t stream) {
    const float* z  = (const float*)d_in[0];
    const float* cb = (const float*)d_in[1];
    float* out = (float*)d_out;
    unsigned char* ws = (unsigned char*)d_ws;

    int*   counter = (int*)(ws + CTR_OFF);
    float* csq     = (float*)(ws + CSQ_OFF);
    unsigned char* cbh = ws + CBH_OFF;
    unsigned char* cbl = ws + CBL_OFF;
    int* list  = (int*)(ws + LIST_OFF);

    prep_csq<<<K_CB / 256, 256, 0, stream>>>(cb, csq);
    prep_split<<<(K_CB * 8) / 256, 256, 0, stream>>>(cb, cbh, cbl);
    init_counter<<<1, 64, 0, stream>>>(counter);
    vq_main_mfma<<<N_ROWS / 128, 256, 0, stream>>>(z, cb, cbh, cbl, csq, list, counter, out);
    repair_kernel<<<1024, 256, 0, stream>>>(z, cb, csq, list, counter, out);
}